// Round 6
// baseline (253.306 us; speedup 1.0000x reference)
//
#include <hip/hip_runtime.h>
#include <cstddef>
#include <cstdint>

#define Bz 4
#define Sz 1024
#define Dm 256
#define Hh 8
#define DHh 2048
#define SCALE 0.0625f

typedef __attribute__((ext_vector_type(8))) short short8;
typedef __attribute__((ext_vector_type(16))) float f32x16;

__device__ inline unsigned short f2bf(float f){
  unsigned u = __float_as_uint(f);
  u += 0x7FFFu + ((u >> 16) & 1u);           // round-to-nearest-even
  return (unsigned short)(u >> 16);
}
__device__ inline unsigned pk2(float a, float b){
  return (unsigned)f2bf(a) | ((unsigned)f2bf(b) << 16);
}
__device__ inline void gll16(const void* g, void* l){
  __builtin_amdgcn_global_load_lds((const __attribute__((address_space(1))) unsigned*)g,
                                   (__attribute__((address_space(3))) unsigned*)l, 16, 0, 0);
}
__device__ inline short8 lds8(const char* p){ return *(const short8*)p; }
__device__ inline f32x16 MM(short8 a, short8 b, f32x16 c){
  return __builtin_amdgcn_mfma_f32_32x32x16_bf16(a, b, c, 0, 0, 0);
}
__device__ inline f32x16 z16(){ f32x16 v;
#pragma unroll
  for(int i=0;i<16;i++) v[i]=0.f; return v; }

// ---------------- fused converts: 3 activations + 4 weight transposes -------
__global__ __launch_bounds__(256) void cvt_all(
    const float* __restrict__ S0, const float* __restrict__ S1, const float* __restrict__ S2,
    unsigned short* __restrict__ D0, unsigned short* __restrict__ D1, unsigned short* __restrict__ D2,
    const float* __restrict__ W0, const float* __restrict__ W1,
    const float* __restrict__ W2, const float* __restrict__ W3,
    unsigned short* __restrict__ T0, unsigned short* __restrict__ T1,
    unsigned short* __restrict__ T2, unsigned short* __restrict__ T3){
  __shared__ float t[32][33];
  int bx = blockIdx.x;
  if(bx < 3072){                             // activation fp32 -> bf16
    const int seg = bx >> 10;
    const float* src = seg==0 ? S0 : seg==1 ? S1 : S2;
    unsigned short* dst = seg==0 ? D0 : seg==1 ? D1 : D2;
    const int i = (bx & 1023)*256 + threadIdx.x;
    float4 v = ((const float4*)src)[i];
    ushort4 o; o.x=f2bf(v.x); o.y=f2bf(v.y); o.z=f2bf(v.z); o.w=f2bf(v.w);
    ((ushort4*)dst)[i] = o;
    return;
  }
  bx -= 3072;                                // weight W[K][N] -> Wt[N][K] bf16
  const int z = bx >> 9, inner = bx & 511;
  const float* W = z==0 ? W0 : z==1 ? W1 : z==2 ? W2 : W3;
  unsigned short* T = z==0 ? T0 : z==1 ? T1 : z==2 ? T2 : T3;
  const int K = (z<3) ? 256 : 2048;
  const int N = (z<3) ? 2048 : 256;
  const int n0 = (z<3) ? (inner & 63)*32 : (inner & 7)*32;
  const int k0 = (z<3) ? (inner >> 6)*32 : (inner >> 3)*32;
  const int a = threadIdx.x >> 5, c = threadIdx.x & 31;
#pragma unroll
  for(int p=0;p<4;p++)
    t[a + p*8][c] = W[(size_t)(k0 + a + p*8)*N + n0 + c];
  __syncthreads();
#pragma unroll
  for(int p=0;p<4;p++)
    T[(size_t)(n0 + a + p*8)*K + k0 + c] = f2bf(t[c][a + p*8]);
}

// ---------------- fused projection GEMMs: z in {0:V->vt, 1:K->kb(xSCALE), 2:Q->qb}
// C[4096 x 2048] = A[4096x256] @ W + bias. Tile 128x128, BK=64, 4 warps,
// double-buffered gll16 staging (1 barrier / K-step).
__global__ __launch_bounds__(256) void gemm_proj_all(
    const unsigned short* __restrict__ A0, const unsigned short* __restrict__ A1,
    const unsigned short* __restrict__ A2,
    const unsigned short* __restrict__ B0, const unsigned short* __restrict__ B1,
    const unsigned short* __restrict__ B2,
    const float* __restrict__ bias0, const float* __restrict__ bias1,
    const float* __restrict__ bias2,
    unsigned short* __restrict__ C0, unsigned short* __restrict__ C1,
    unsigned short* __restrict__ C2){
  __shared__ __align__(16) char sm[65536];   // [db][A 16K | B 16K]
  const int z = blockIdx.z;
  const unsigned short* A = z==0 ? A0 : z==1 ? A1 : A2;
  const unsigned short* Bt = z==0 ? B0 : z==1 ? B1 : B2;
  const float* bias = z==0 ? bias0 : z==1 ? bias1 : bias2;
  unsigned short* C = z==0 ? C0 : z==1 ? C1 : C2;
  const int tid = threadIdx.x, w = tid>>6, lane = tid&63, l31 = lane&31, hp = lane>>5;
  const int wm = (w>>1)*64, wn = (w&1)*64;
  const int bm = blockIdx.y*128, bn = blockIdx.x*128;
  f32x16 acc[2][2]; acc[0][0]=z16(); acc[0][1]=z16(); acc[1][0]=z16(); acc[1][1]=z16();

  auto STAGE = [&](int db, int kk){
#pragma unroll
    for(int j=0;j<4;j++){
      int ci = (w*4+j)*64 + lane;          // 0..1023
      int m = ci>>3, sl = ci&7;
      gll16(A  + (size_t)(bm+m)*256 + kk + ((sl ^ (m&7))<<3), sm + db*32768 + (w*4+j)*1024);
      gll16(Bt + (size_t)(bn+m)*256 + kk + ((sl ^ (m&7))<<3), sm + db*32768 + 16384 + (w*4+j)*1024);
    }
  };

  STAGE(0, 0);
  __syncthreads();
  int db = 0;
  for(int t=0; t<4; ++t){
    if(t<3) STAGE(db^1, (t+1)*64);
    const char* base = sm + db*32768;
#pragma unroll
    for(int s=0;s<4;s++){
      int m0 = wm + l31, m1 = wm + 32 + l31;
      int n0 = wn + l31, n1 = wn + 32 + l31;
      short8 a0 = lds8(base + m0*128 + (((s*2+hp) ^ (m0&7))<<4));
      short8 a1 = lds8(base + m1*128 + (((s*2+hp) ^ (m1&7))<<4));
      short8 b0 = lds8(base + 16384 + n0*128 + (((s*2+hp) ^ (n0&7))<<4));
      short8 b1 = lds8(base + 16384 + n1*128 + (((s*2+hp) ^ (n1&7))<<4));
      acc[0][0] = MM(a0,b0,acc[0][0]); acc[0][1] = MM(a0,b1,acc[0][1]);
      acc[1][0] = MM(a1,b0,acc[1][0]); acc[1][1] = MM(a1,b1,acc[1][1]);
    }
    __syncthreads();
    db ^= 1;
  }
#pragma unroll
  for(int nh=0; nh<2; nh++){
    int ncol = bn + wn + nh*32 + l31;
    float bb = bias[ncol];
#pragma unroll
    for(int mh=0; mh<2; mh++){
      if(z == 0){                            // V: transposed store vt[b][h][d][s]
        int hidx = ncol >> 8, d = ncol & 255;
#pragma unroll
        for(int gq=0; gq<4; gq++){
          int mrow = bm + wm + mh*32 + 8*gq + 4*hp;
          int batch = mrow >> 10, sin = mrow & 1023;
          unsigned u0 = pk2(acc[mh][nh][4*gq+0] + bb, acc[mh][nh][4*gq+1] + bb);
          unsigned u1 = pk2(acc[mh][nh][4*gq+2] + bb, acc[mh][nh][4*gq+3] + bb);
          uint2 uu; uu.x = u0; uu.y = u1;
          *(uint2*)(C + ((size_t)((batch*Hh + hidx)*Dm + d))*Sz + sin) = uu;
        }
      } else {
        float sc = (z == 1) ? SCALE : 1.0f;
#pragma unroll
        for(int r=0; r<16; r++){
          int mrow = bm + wm + mh*32 + (r&3) + 8*(r>>2) + 4*hp;
          C[(size_t)mrow*DHh + ncol] = f2bf((acc[mh][nh][r] + bb) * sc);
        }
      }
    }
  }
}

// ---------------- flash attention (bf16 MFMA) -------------------------------
// S[r][c] = <Kp[r]*SCALE, Qp[c]> (SCALE folded into Kp), softmax over c,
// O[r][d] = sum_c P V[c][d].  Swapped QK^T (lane-local row stats).
// 512 blocks x 256 thr (4 warps = 2 rg x 2 KV-halves), 64 rows/block,
// single-buffered 64KB LDS -> 2 independent blocks/CU (2 barrier domains).
// XCD swizzle: per XCD, 4 (b,h) groups x 16 row-blocks.
__global__ __launch_bounds__(256, 2) void attn_mfma(
    const unsigned short* __restrict__ Kp, const unsigned short* __restrict__ Qp,
    const unsigned short* __restrict__ Vt, unsigned short* __restrict__ Oc){
  __shared__ __align__(16) char sm[66560];
  // loop:  Qp set s at [s*16K, +16K) | Vt set s at [32K + s*16K, +16K)
  // merge: [rg*32K, +32K) = [32 r][256 d] f32 ; stats f32[4][32][2] at 64K
  const int tid = threadIdx.x, w = tid>>6, lane = tid&63, l31 = lane&31, hp = lane>>5;
  const int rg = w&1, set = w>>1;
  const int bid = blockIdx.x;
  const int xcd = bid & 7, inner = bid >> 3;
  const int rb = inner & 15, gsub = inner >> 4;
  const int g = gsub*8 + xcd, b = g >> 3, h = g & 7;
  const int brow0 = rb * 64;
  const size_t vtbase = ((size_t)((b*Hh + h)*Dm))*Sz;

  // K rows of this row-group as B-op fragments (col=lane&31=r, k=(lane>>5)*8+j)
  short8 kp[16];
  {
    const unsigned short* kr = Kp + (size_t)(b*Sz + brow0 + rg*32 + l31)*DHh + h*Dm + hp*8;
#pragma unroll
    for(int ki=0; ki<16; ki++) kp[ki] = *(const short8*)(kr + ki*16);
  }
  f32x16 acc[8];
#pragma unroll
  for(int f=0; f<8; f++) acc[f] = z16();
  float m_run = -3.0e38f, l_run = 0.f;
  char* qpL = sm + set*16384;
  char* vtL = sm + 32768 + set*16384;

  auto STAGE = [&](int it){
    const int kv0 = set*512 + it*32;
#pragma unroll
    for(int j=0; j<8; j++){
      int slot = j*2 + rg;                 // 16 slots x 1KB per buffer
      int ci = slot*64 + lane;             // 0..1023
      int c = ci>>5, sl5 = ci&31;
      gll16(Qp + (size_t)(b*Sz + kv0 + c)*DHh + h*Dm + ((sl5 ^ c)<<3),
            qpL + slot*1024);
      int dp = ci>>3, sv = (ci&7) ^ (dp&7);
      int d = dp*2 + (sv>>2), co = (sv&3)*8;
      gll16(Vt + vtbase + (size_t)d*Sz + kv0 + co, vtL + slot*1024);
    }
  };

  STAGE(0);
  __syncthreads();
  for(int it=0; it<16; ++it){
    // QK^T: T[32c][32r], A = Qp frags, B = kp regs
    f32x16 S = z16();
#pragma unroll
    for(int ki=0; ki<16; ki++){
      short8 a = lds8(qpL + l31*512 + (((ki*2+hp) ^ l31)<<4));
      S = MM(a, kp[ki], S);
    }
    // online softmax, lane-local for r = l31 (c-halves joined via shfl_xor 32)
    float tmax = S[0];
#pragma unroll
    for(int r=1; r<16; r++) tmax = fmaxf(tmax, S[r]);
    tmax = fmaxf(tmax, __shfl_xor(tmax, 32));
    if(!__all(tmax <= m_run + 8.0f)){
      float mnew = fmaxf(m_run, tmax);
      float alpha = __expf(m_run - mnew);
      m_run = mnew; l_run *= alpha;
#pragma unroll
      for(int r=0; r<16; r++){
        int rr = (r&3) + 8*(r>>2) + 4*hp;
        float ar = __shfl(alpha, rr);
#pragma unroll
        for(int f=0; f<8; f++) acc[f][r] *= ar;
      }
    }
    float lsum = 0.f;
#pragma unroll
    for(int r=0; r<16; r++){ S[r] = __expf(S[r] - m_run); lsum += S[r]; }
    lsum += __shfl_xor(lsum, 32);
    l_run += lsum;
    // pack P -> bf16 A-op frags (row=lane&31=r, k=c), halves joined via shfl
    short8 pa[2];
#pragma unroll
    for(int t=0; t<2; t++){
      unsigned w01 = pk2(S[t*8+0], S[t*8+1]);
      unsigned w23 = pk2(S[t*8+2], S[t*8+3]);
      unsigned w45 = pk2(S[t*8+4], S[t*8+5]);
      unsigned w67 = pk2(S[t*8+6], S[t*8+7]);
      unsigned x01 = __shfl_xor(w01, 32), x23 = __shfl_xor(w23, 32);
      unsigned x45 = __shfl_xor(w45, 32), x67 = __shfl_xor(w67, 32);
      union { unsigned u[4]; short8 s8; } U;
      if(hp == 0){ U.u[0]=w01; U.u[1]=w23; U.u[2]=x01; U.u[3]=x23; }
      else       { U.u[0]=x45; U.u[1]=x67; U.u[2]=w45; U.u[3]=w67; }
      pa[t] = U.s8;
    }
    // PV: acc[f] += P[32r x 16c] @ V[16c x 32d]
#pragma unroll
    for(int t=0; t<2; t++){
#pragma unroll
      for(int f=0; f<8; f++){
        int d = f*32 + l31;
        int dp = d>>1;
        int slot = (d&1)*4 + t*2 + hp;
        short8 vfr = lds8(vtL + dp*128 + ((slot ^ (dp&7))<<4));
        acc[f] = MM(pa[t], vfr, acc[f]);
      }
    }
    if(it < 15){
      __syncthreads();                     // all warps done reading tile it
      STAGE(it+1);                         // overwrite with tile it+1
      __syncthreads();                     // vmcnt drain -> tile ready
    }
  }
  // ---- merge the two KV halves, then store bf16 concat ----
  __syncthreads();
  float* stats = (float*)(sm + 65536);
  if(lane < 32){ stats[(w*32 + lane)*2 + 0] = m_run; stats[(w*32 + lane)*2 + 1] = l_run; }
  __syncthreads();
  float* mg = (float*)sm + rg*8192;        // [32 r][256 d] f32 for this rg
  if(set == 1){
    float mA = stats[(rg*32 + l31)*2 + 0];
    float mf = fmaxf(mA, m_run);
    float bB = __expf(m_run - mf);
#pragma unroll
    for(int r=0; r<16; r++){
      int rr = (r&3) + 8*(r>>2) + 4*hp;
      float br = __shfl(bB, rr);
#pragma unroll
      for(int f=0; f<8; f++) mg[rr*256 + f*32 + l31] = acc[f][r]*br;
    }
  }
  __syncthreads();
  if(set == 0){
    float mB = stats[((2+rg)*32 + l31)*2 + 0];
    float lB = stats[((2+rg)*32 + l31)*2 + 1];
    float mf = fmaxf(m_run, mB);
    float bA = __expf(m_run - mf), bBv = __expf(mB - mf);
    float inv = 1.0f / (l_run*bA + lB*bBv);
#pragma unroll
    for(int r=0; r<16; r++){
      int rr = (r&3) + 8*(r>>2) + 4*hp;
      float bAr = __shfl(bA, rr);
      float invr = __shfl(inv, rr);
      int srow = brow0 + rg*32 + rr;
#pragma unroll
      for(int f=0; f<8; f++){
        float v = (acc[f][r]*bAr + mg[rr*256 + f*32 + l31]) * invr;
        Oc[(size_t)(b*Sz + srow)*DHh + h*Dm + f*32 + l31] = f2bf(v);
      }
    }
  }
}

// ---------------- output GEMM: out[4096x256] = concat[4096x2048] @ Wo + bo ---
// concat bf16, Wot bf16 [256][2048]; 4 warps, 64x64 tile, BK=64, double-buffered.
__global__ __launch_bounds__(256) void gemm_out(const unsigned short* __restrict__ A,
    const unsigned short* __restrict__ Bt, const float* __restrict__ bias,
    float* __restrict__ C){
  __shared__ __align__(16) char sm[32768];   // [db][A 8K | B 8K]
  const int tid = threadIdx.x, w = tid>>6, lane = tid&63, l31 = lane&31, hp = lane>>5;
  const int wm = (w>>1)*32, wn = (w&1)*32;
  const int bm = blockIdx.y*64, bn = blockIdx.x*64;
  f32x16 acc = z16();

  auto STAGE = [&](int db, int kk){
#pragma unroll
    for(int j=0; j<2; j++){
      int ci = (w*2+j)*64 + lane;          // 0..511
      int m = ci>>3, sl = ci&7;
      gll16(A  + (size_t)(bm+m)*DHh + kk + ((sl ^ (m&7))<<3), sm + db*16384 + (w*2+j)*1024);
      gll16(Bt + (size_t)(bn+m)*DHh + kk + ((sl ^ (m&7))<<3), sm + db*16384 + 8192 + (w*2+j)*1024);
    }
  };

  STAGE(0, 0);
  __syncthreads();
  int db = 0;
  for(int t=0; t<32; ++t){
    if(t<31) STAGE(db^1, (t+1)*64);
    const char* base = sm + db*16384;
#pragma unroll
    for(int s=0; s<4; s++){
      int m0 = wm + l31, n0 = wn + l31;
      short8 a = lds8(base + m0*128 + (((s*2+hp) ^ (m0&7))<<4));
      short8 b = lds8(base + 8192 + n0*128 + (((s*2+hp) ^ (n0&7))<<4));
      acc = MM(a, b, acc);
    }
    __syncthreads();
    db ^= 1;
  }
  float bb = bias[bn + wn + l31];
#pragma unroll
  for(int r=0; r<16; r++){
    int mrow = bm + wm + (r&3) + 8*(r>>2) + 4*hp;
    C[(size_t)mrow*Dm + bn + wn + l31] = acc[r] + bb;
  }
}

extern "C" void kernel_launch(void* const* d_in, const int* in_sizes, int n_in,
                              void* d_out, int out_size, void* d_ws, size_t ws_size,
                              hipStream_t stream){
  (void)in_sizes; (void)n_in; (void)out_size; (void)ws_size;
  const float* value_in = (const float*)d_in[0];
  const float* key_in   = (const float*)d_in[1];
  const float* query_in = (const float*)d_in[2];
  const float* Wv = (const float*)d_in[3];
  const float* bv = (const float*)d_in[4];
  const float* Wk = (const float*)d_in[5];
  const float* bk = (const float*)d_in[6];
  const float* Wq = (const float*)d_in[7];
  const float* bq = (const float*)d_in[8];
  const float* Wo = (const float*)d_in[9];
  const float* bo = (const float*)d_in[10];

  char* ws = (char*)d_ws;
  unsigned short* av  = (unsigned short*)(ws + ((size_t) 0u<<20));  // 2MB
  unsigned short* ak  = (unsigned short*)(ws + ((size_t) 2u<<20));  // 2MB
  unsigned short* aq  = (unsigned short*)(ws + ((size_t) 4u<<20));  // 2MB
  unsigned short* wtv = (unsigned short*)(ws + ((size_t) 6u<<20));  // 1MB
  unsigned short* wtk = (unsigned short*)(ws + ((size_t) 7u<<20));  // 1MB
  unsigned short* wtq = (unsigned short*)(ws + ((size_t) 8u<<20));  // 1MB
  unsigned short* wto = (unsigned short*)(ws + ((size_t) 9u<<20));  // 1MB
  unsigned short* vt  = (unsigned short*)(ws + ((size_t)10u<<20));  // 16MB [b][h][d][s]
  unsigned short* kb  = (unsigned short*)(ws + ((size_t)26u<<20));  // 16MB (pre-scaled)
  unsigned short* qb  = (unsigned short*)(ws + ((size_t)42u<<20));  // 16MB
  unsigned short* cc  = (unsigned short*)(ws + ((size_t)58u<<20));  // 16MB concat

  cvt_all<<<5120, 256, 0, stream>>>(value_in, key_in, query_in, av, ak, aq,
                                    Wv, Wk, Wq, Wo, wtv, wtk, wtq, wto);

  gemm_proj_all<<<dim3(16, 32, 3), 256, 0, stream>>>(
      av, ak, aq, wtv, wtk, wtq, bv, bk, bq, vt, kb, qb);

  attn_mfma<<<512, 256, 0, stream>>>(kb, qb, vt, cc);

  gemm_out<<<dim3(4, 64), 256, 0, stream>>>(cc, wto, bo, (float*)d_out);
}

// Round 7
// 209.771 us; speedup vs baseline: 1.2075x; 1.2075x over previous
//
#include <hip/hip_runtime.h>
#include <cstddef>
#include <cstdint>

#define Bz 4
#define Sz 1024
#define Dm 256
#define Hh 8
#define DHh 2048
#define SCALE 0.0625f

typedef __attribute__((ext_vector_type(8))) short short8;
typedef __attribute__((ext_vector_type(16))) float f32x16;

__device__ inline unsigned short f2bf(float f){
  unsigned u = __float_as_uint(f);
  u += 0x7FFFu + ((u >> 16) & 1u);           // round-to-nearest-even
  return (unsigned short)(u >> 16);
}
__device__ inline unsigned pk2(float a, float b){
  return (unsigned)f2bf(a) | ((unsigned)f2bf(b) << 16);
}
__device__ inline void gll16(const void* g, void* l){
  __builtin_amdgcn_global_load_lds((const __attribute__((address_space(1))) unsigned*)g,
                                   (__attribute__((address_space(3))) unsigned*)l, 16, 0, 0);
}
__device__ inline short8 lds8(const char* p){ return *(const short8*)p; }
__device__ inline f32x16 MM(short8 a, short8 b, f32x16 c){
  return __builtin_amdgcn_mfma_f32_32x32x16_bf16(a, b, c, 0, 0, 0);
}
__device__ inline f32x16 z16(){ f32x16 v;
#pragma unroll
  for(int i=0;i<16;i++) v[i]=0.f; return v; }

// ---------------- fused converts: 3 activations + 4 weight transposes -------
__global__ __launch_bounds__(256) void cvt_all(
    const float* __restrict__ S0, const float* __restrict__ S1, const float* __restrict__ S2,
    unsigned short* __restrict__ D0, unsigned short* __restrict__ D1, unsigned short* __restrict__ D2,
    const float* __restrict__ W0, const float* __restrict__ W1,
    const float* __restrict__ W2, const float* __restrict__ W3,
    unsigned short* __restrict__ T0, unsigned short* __restrict__ T1,
    unsigned short* __restrict__ T2, unsigned short* __restrict__ T3){
  __shared__ float t[32][33];
  int bx = blockIdx.x;
  if(bx < 3072){                             // activation fp32 -> bf16
    const int seg = bx >> 10;
    const float* src = seg==0 ? S0 : seg==1 ? S1 : S2;
    unsigned short* dst = seg==0 ? D0 : seg==1 ? D1 : D2;
    const int i = (bx & 1023)*256 + threadIdx.x;
    float4 v = ((const float4*)src)[i];
    ushort4 o; o.x=f2bf(v.x); o.y=f2bf(v.y); o.z=f2bf(v.z); o.w=f2bf(v.w);
    ((ushort4*)dst)[i] = o;
    return;
  }
  bx -= 3072;                                // weight W[K][N] -> Wt[N][K] bf16
  const int z = bx >> 9, inner = bx & 511;
  const float* W = z==0 ? W0 : z==1 ? W1 : z==2 ? W2 : W3;
  unsigned short* T = z==0 ? T0 : z==1 ? T1 : z==2 ? T2 : T3;
  const int K = (z<3) ? 256 : 2048;
  const int N = (z<3) ? 2048 : 256;
  const int n0 = (z<3) ? (inner & 63)*32 : (inner & 7)*32;
  const int k0 = (z<3) ? (inner >> 6)*32 : (inner >> 3)*32;
  const int a = threadIdx.x >> 5, c = threadIdx.x & 31;
#pragma unroll
  for(int p=0;p<4;p++)
    t[a + p*8][c] = W[(size_t)(k0 + a + p*8)*N + n0 + c];
  __syncthreads();
#pragma unroll
  for(int p=0;p<4;p++)
    T[(size_t)(n0 + a + p*8)*K + k0 + c] = f2bf(t[c][a + p*8]);
}

// ---------------- fused projection GEMMs: z in {0:V->v8, 1:K->kb(xSCALE), 2:Q->qb}
// C[4096 x 2048] = A[4096x256] @ W + bias. Tile 128x128, BK=64, 4 warps,
// double-buffered gll16 staging (1 barrier / K-step).
// V output layout: v8[b][h][s>>3][d][s&7]  (8-deep s-minitiles, d-major)
__global__ __launch_bounds__(256) void gemm_proj_all(
    const unsigned short* __restrict__ A0, const unsigned short* __restrict__ A1,
    const unsigned short* __restrict__ A2,
    const unsigned short* __restrict__ B0, const unsigned short* __restrict__ B1,
    const unsigned short* __restrict__ B2,
    const float* __restrict__ bias0, const float* __restrict__ bias1,
    const float* __restrict__ bias2,
    unsigned short* __restrict__ C0, unsigned short* __restrict__ C1,
    unsigned short* __restrict__ C2){
  __shared__ __align__(16) char sm[65536];   // [db][A 16K | B 16K]
  const int z = blockIdx.z;
  const unsigned short* A = z==0 ? A0 : z==1 ? A1 : A2;
  const unsigned short* Bt = z==0 ? B0 : z==1 ? B1 : B2;
  const float* bias = z==0 ? bias0 : z==1 ? bias1 : bias2;
  unsigned short* C = z==0 ? C0 : z==1 ? C1 : C2;
  const int tid = threadIdx.x, w = tid>>6, lane = tid&63, l31 = lane&31, hp = lane>>5;
  const int wm = (w>>1)*64, wn = (w&1)*64;
  const int bm = blockIdx.y*128, bn = blockIdx.x*128;
  f32x16 acc[2][2]; acc[0][0]=z16(); acc[0][1]=z16(); acc[1][0]=z16(); acc[1][1]=z16();

  auto STAGE = [&](int db, int kk){
#pragma unroll
    for(int j=0;j<4;j++){
      int ci = (w*4+j)*64 + lane;          // 0..1023
      int m = ci>>3, sl = ci&7;
      gll16(A  + (size_t)(bm+m)*256 + kk + ((sl ^ (m&7))<<3), sm + db*32768 + (w*4+j)*1024);
      gll16(Bt + (size_t)(bn+m)*256 + kk + ((sl ^ (m&7))<<3), sm + db*32768 + 16384 + (w*4+j)*1024);
    }
  };

  STAGE(0, 0);
  __syncthreads();
  int db = 0;
  for(int t=0; t<4; ++t){
    if(t<3) STAGE(db^1, (t+1)*64);
    const char* base = sm + db*32768;
#pragma unroll
    for(int s=0;s<4;s++){
      int m0 = wm + l31, m1 = wm + 32 + l31;
      int n0 = wn + l31, n1 = wn + 32 + l31;
      short8 a0 = lds8(base + m0*128 + (((s*2+hp) ^ (m0&7))<<4));
      short8 a1 = lds8(base + m1*128 + (((s*2+hp) ^ (m1&7))<<4));
      short8 b0 = lds8(base + 16384 + n0*128 + (((s*2+hp) ^ (n0&7))<<4));
      short8 b1 = lds8(base + 16384 + n1*128 + (((s*2+hp) ^ (n1&7))<<4));
      acc[0][0] = MM(a0,b0,acc[0][0]); acc[0][1] = MM(a0,b1,acc[0][1]);
      acc[1][0] = MM(a1,b0,acc[1][0]); acc[1][1] = MM(a1,b1,acc[1][1]);
    }
    __syncthreads();
    db ^= 1;
  }
#pragma unroll
  for(int nh=0; nh<2; nh++){
    int ncol = bn + wn + nh*32 + l31;
    float bb = bias[ncol];
#pragma unroll
    for(int mh=0; mh<2; mh++){
      if(z == 0){                            // V: v8[b][h][s>>3][d][s&7]
        int hidx = ncol >> 8, d = ncol & 255;
#pragma unroll
        for(int gq=0; gq<4; gq++){
          int mrow = bm + wm + mh*32 + 8*gq + 4*hp;   // 4 consecutive s at fixed d
          int batch = mrow >> 10, sin = mrow & 1023;
          int sblk = sin >> 3;
          unsigned u0 = pk2(acc[mh][nh][4*gq+0] + bb, acc[mh][nh][4*gq+1] + bb);
          unsigned u1 = pk2(acc[mh][nh][4*gq+2] + bb, acc[mh][nh][4*gq+3] + bb);
          uint2 uu; uu.x = u0; uu.y = u1;
          *(uint2*)(C + ((size_t)((batch*Hh + hidx)*128 + sblk)*256 + d)*8 + 4*hp) = uu;
        }
      } else {
        float sc = (z == 1) ? SCALE : 1.0f;
#pragma unroll
        for(int r=0; r<16; r++){
          int mrow = bm + wm + mh*32 + (r&3) + 8*(r>>2) + 4*hp;
          C[(size_t)mrow*DHh + ncol] = f2bf((acc[mh][nh][r] + bb) * sc);
        }
      }
    }
  }
}

// ---------------- flash attention (bf16 MFMA) -------------------------------
// S[r][c] = <Kp[r]*SCALE, Qp[c]> (SCALE folded into Kp), softmax over c,
// O[r][d] = sum_c P V[c][d].  Swapped QK^T (lane-local row stats).
// R4 skeleton: 256 blocks x 512 thr, 8 warps = 4 rg x 2 KV-halves, 128 rows/blk,
// Q double-buffered in LDS (prefetch at top, 1 barrier/iter).
// NEW: V streamed global->regs from v8[b][h][s>>3][d][s&7] (coalesced 16B/lane,
// no barrier dependency, compiler-counted vmcnt) -> half the staged bytes,
// no PV LDS reads, LDS 66KB. T5 setprio around MFMA clusters.
__global__ __launch_bounds__(512, 2) void attn_mfma(
    const unsigned short* __restrict__ Kp, const unsigned short* __restrict__ Qp,
    const unsigned short* __restrict__ Vt, unsigned short* __restrict__ Oc){
  __shared__ __align__(16) char sm[67584];
  // loop:  Q db at [db*32K + set*16K, +16K)
  // merge: stats f32[8][32][2] at 64K; pair-buffer [2][32][256] f32 in [0,64K)
  const int tid = threadIdx.x, w = tid>>6, lane = tid&63, l31 = lane&31, hp = lane>>5;
  const int set = w>>2, ws = w&3;
  const int bid = blockIdx.x;
  const int g = (bid & 7)*4 + (bid >> 6);    // XCD-local (b,h) groups
  const int b = g >> 3, h = g & 7;
  const int brow0 = ((bid >> 3) & 7) * 128;
  const size_t vtbase = (size_t)(b*Hh + h) * (Sz*Dm);

  // K rows of this row-group as B-op fragments (col=lane&31=r, k=(lane>>5)*8+j)
  short8 kp[16];
  {
    const unsigned short* kr = Kp + (size_t)(b*Sz + brow0 + ws*32 + l31)*DHh + h*Dm + hp*8;
#pragma unroll
    for(int ki=0; ki<16; ki++) kp[ki] = *(const short8*)(kr + ki*16);
  }
  f32x16 acc[8];
#pragma unroll
  for(int f=0; f<8; f++) acc[f] = z16();
  float m_run = -3.0e38f, l_run = 0.f;

  auto STAGE = [&](int db, int it){
    const int kv0 = set*512 + it*32;
    char* qpD = sm + db*32768 + set*16384;
#pragma unroll
    for(int j=0; j<4; j++){
      int slot = ws*4 + j;                 // 16 slots x 1KB per set-buffer
      int ci = slot*64 + lane;             // 0..1023
      int c = ci>>5, sl5 = ci&31;
      gll16(Qp + (size_t)(b*Sz + kv0 + c)*DHh + h*Dm + ((sl5 ^ c)<<3),
            qpD + slot*1024);
    }
  };

  STAGE(0, 0);
  __syncthreads();
  int db = 0;
  for(int it=0; it<16; ++it){
    if(it<15) STAGE(db^1, it+1);         // prefetch next Q tile (drained by barrier)
    const char* qpL = sm + db*32768 + set*16384;
    // QK^T: T[32c][32r], A = Qp frags, B = kp regs
    f32x16 S = z16();
    __builtin_amdgcn_s_setprio(1);
#pragma unroll
    for(int ki=0; ki<16; ki++){
      short8 a = lds8(qpL + l31*512 + (((ki*2+hp) ^ l31)<<4));
      S = MM(a, kp[ki], S);
    }
    __builtin_amdgcn_s_setprio(0);
    // online softmax, lane-local for r = l31 (c-halves joined via shfl_xor 32)
    float tmax = S[0];
#pragma unroll
    for(int r=1; r<16; r++) tmax = fmaxf(tmax, S[r]);
    tmax = fmaxf(tmax, __shfl_xor(tmax, 32));
    if(!__all(tmax <= m_run + 8.0f)){
      float mnew = fmaxf(m_run, tmax);
      float alpha = __expf(m_run - mnew);
      m_run = mnew; l_run *= alpha;
#pragma unroll
      for(int r=0; r<16; r++){
        int rr = (r&3) + 8*(r>>2) + 4*hp;
        float ar = __shfl(alpha, rr);
#pragma unroll
        for(int f=0; f<8; f++) acc[f][r] *= ar;
      }
    }
    float lsum = 0.f;
#pragma unroll
    for(int r=0; r<16; r++){ S[r] = __expf(S[r] - m_run); lsum += S[r]; }
    lsum += __shfl_xor(lsum, 32);
    l_run += lsum;
    // pack P -> bf16 A-op frags (row=lane&31=r, k=c), halves joined via shfl
    short8 pa[2];
#pragma unroll
    for(int t=0; t<2; t++){
      unsigned w01 = pk2(S[t*8+0], S[t*8+1]);
      unsigned w23 = pk2(S[t*8+2], S[t*8+3]);
      unsigned w45 = pk2(S[t*8+4], S[t*8+5]);
      unsigned w67 = pk2(S[t*8+6], S[t*8+7]);
      unsigned x01 = __shfl_xor(w01, 32), x23 = __shfl_xor(w23, 32);
      unsigned x45 = __shfl_xor(w45, 32), x67 = __shfl_xor(w67, 32);
      union { unsigned u[4]; short8 s8; } U;
      if(hp == 0){ U.u[0]=w01; U.u[1]=w23; U.u[2]=x01; U.u[3]=x23; }
      else       { U.u[0]=x45; U.u[1]=x67; U.u[2]=w45; U.u[3]=w67; }
      pa[t] = U.s8;
    }
    // PV: acc[f] += P[32r x 16c] @ V[16c x 32d], V streamed from global (v8 layout)
    const int sb0 = set*64 + it*4;         // s-miniblock base of this tile
#pragma unroll
    for(int t=0; t<2; t++){
      const unsigned short* vrow = Vt + vtbase + (size_t)(sb0 + t*2 + hp)*2048;
      short8 vf[8];
#pragma unroll
      for(int f=0; f<8; f++)
        vf[f] = *(const short8*)(vrow + (f*32 + l31)*8);
      __builtin_amdgcn_s_setprio(1);
#pragma unroll
      for(int f=0; f<8; f++) acc[f] = MM(pa[t], vf[f], acc[f]);
      __builtin_amdgcn_s_setprio(0);
    }
    __syncthreads();                     // drains Q prefetch + guards buffer swap
    db ^= 1;
  }
  // ---- merge the two KV halves (2-pass over rg pairs to fit 64KB), store ----
  __syncthreads();
  float* stats = (float*)(sm + 65536);
  if(lane < 32){ stats[(w*32 + lane)*2 + 0] = m_run; stats[(w*32 + lane)*2 + 1] = l_run; }
#pragma unroll
  for(int p=0; p<2; p++){
    __syncthreads();
    if(set == 1 && (ws>>1) == p){
      float mA = stats[(ws*32 + l31)*2 + 0];
      float mf = fmaxf(mA, m_run);
      float bB = __expf(m_run - mf);
      float* mg = (float*)sm + (ws&1)*8192;      // [32 r][256 d] f32
#pragma unroll
      for(int r=0; r<16; r++){
        int rr = (r&3) + 8*(r>>2) + 4*hp;
        float br = __shfl(bB, rr);
#pragma unroll
        for(int f=0; f<8; f++) mg[rr*256 + f*32 + l31] = acc[f][r]*br;
      }
    }
    __syncthreads();
    if(set == 0 && (ws>>1) == p){
      float mB = stats[((4+ws)*32 + l31)*2 + 0];
      float lB = stats[((4+ws)*32 + l31)*2 + 1];
      float mf = fmaxf(m_run, mB);
      float bA = __expf(m_run - mf), bBv = __expf(mB - mf);
      float inv = 1.0f / (l_run*bA + lB*bBv);
      float* mg = (float*)sm + (ws&1)*8192;
#pragma unroll
      for(int r=0; r<16; r++){
        int rr = (r&3) + 8*(r>>2) + 4*hp;
        float bAr = __shfl(bA, rr);
        float invr = __shfl(inv, rr);
        int srow = brow0 + ws*32 + rr;
#pragma unroll
        for(int f=0; f<8; f++){
          float v = (acc[f][r]*bAr + mg[rr*256 + f*32 + l31]) * invr;
          Oc[(size_t)(b*Sz + srow)*DHh + h*Dm + f*32 + l31] = f2bf(v);
        }
      }
    }
  }
}

// ---------------- output GEMM: out[4096x256] = concat[4096x2048] @ Wo + bo ---
// concat bf16, Wot bf16 [256][2048]; 4 warps, 64x64 tile, BK=64, double-buffered.
__global__ __launch_bounds__(256) void gemm_out(const unsigned short* __restrict__ A,
    const unsigned short* __restrict__ Bt, const float* __restrict__ bias,
    float* __restrict__ C){
  __shared__ __align__(16) char sm[32768];   // [db][A 8K | B 8K]
  const int tid = threadIdx.x, w = tid>>6, lane = tid&63, l31 = lane&31, hp = lane>>5;
  const int wm = (w>>1)*32, wn = (w&1)*32;
  const int bm = blockIdx.y*64, bn = blockIdx.x*64;
  f32x16 acc = z16();

  auto STAGE = [&](int db, int kk){
#pragma unroll
    for(int j=0; j<2; j++){
      int ci = (w*2+j)*64 + lane;          // 0..511
      int m = ci>>3, sl = ci&7;
      gll16(A  + (size_t)(bm+m)*DHh + kk + ((sl ^ (m&7))<<3), sm + db*16384 + (w*2+j)*1024);
      gll16(Bt + (size_t)(bn+m)*DHh + kk + ((sl ^ (m&7))<<3), sm + db*16384 + 8192 + (w*2+j)*1024);
    }
  };

  STAGE(0, 0);
  __syncthreads();
  int db = 0;
  for(int t=0; t<32; ++t){
    if(t<31) STAGE(db^1, (t+1)*64);
    const char* base = sm + db*16384;
#pragma unroll
    for(int s=0; s<4; s++){
      int m0 = wm + l31, n0 = wn + l31;
      short8 a = lds8(base + m0*128 + (((s*2+hp) ^ (m0&7))<<4));
      short8 b = lds8(base + 8192 + n0*128 + (((s*2+hp) ^ (n0&7))<<4));
      acc = MM(a, b, acc);
    }
    __syncthreads();
    db ^= 1;
  }
  float bb = bias[bn + wn + l31];
#pragma unroll
  for(int r=0; r<16; r++){
    int mrow = bm + wm + (r&3) + 8*(r>>2) + 4*hp;
    C[(size_t)mrow*Dm + bn + wn + l31] = acc[r] + bb;
  }
}

extern "C" void kernel_launch(void* const* d_in, const int* in_sizes, int n_in,
                              void* d_out, int out_size, void* d_ws, size_t ws_size,
                              hipStream_t stream){
  (void)in_sizes; (void)n_in; (void)out_size; (void)ws_size;
  const float* value_in = (const float*)d_in[0];
  const float* key_in   = (const float*)d_in[1];
  const float* query_in = (const float*)d_in[2];
  const float* Wv = (const float*)d_in[3];
  const float* bv = (const float*)d_in[4];
  const float* Wk = (const float*)d_in[5];
  const float* bk = (const float*)d_in[6];
  const float* Wq = (const float*)d_in[7];
  const float* bq = (const float*)d_in[8];
  const float* Wo = (const float*)d_in[9];
  const float* bo = (const float*)d_in[10];

  char* ws = (char*)d_ws;
  unsigned short* av  = (unsigned short*)(ws + ((size_t) 0u<<20));  // 2MB
  unsigned short* ak  = (unsigned short*)(ws + ((size_t) 2u<<20));  // 2MB
  unsigned short* aq  = (unsigned short*)(ws + ((size_t) 4u<<20));  // 2MB
  unsigned short* wtv = (unsigned short*)(ws + ((size_t) 6u<<20));  // 1MB
  unsigned short* wtk = (unsigned short*)(ws + ((size_t) 7u<<20));  // 1MB
  unsigned short* wtq = (unsigned short*)(ws + ((size_t) 8u<<20));  // 1MB
  unsigned short* wto = (unsigned short*)(ws + ((size_t) 9u<<20));  // 1MB
  unsigned short* vt  = (unsigned short*)(ws + ((size_t)10u<<20));  // 16MB v8[b][h][s>>3][d][s&7]
  unsigned short* kb  = (unsigned short*)(ws + ((size_t)26u<<20));  // 16MB (pre-scaled)
  unsigned short* qb  = (unsigned short*)(ws + ((size_t)42u<<20));  // 16MB
  unsigned short* cc  = (unsigned short*)(ws + ((size_t)58u<<20));  // 16MB concat

  cvt_all<<<5120, 256, 0, stream>>>(value_in, key_in, query_in, av, ak, aq,
                                    Wv, Wk, Wq, Wo, wtv, wtk, wtq, wto);

  gemm_proj_all<<<dim3(16, 32, 3), 256, 0, stream>>>(
      av, ak, aq, wtv, wtk, wtq, bv, bk, bq, vt, kb, qb);

  attn_mfma<<<256, 512, 0, stream>>>(kb, qb, vt, cc);

  gemm_out<<<dim3(4, 64), 256, 0, stream>>>(cc, wto, bo, (float*)d_out);
}